// Round 1
// 72.864 us; speedup vs baseline: 1.0082x; 1.0082x over previous
//
#include <hip/hip_runtime.h>
#include <math.h>

#define D  16     // latent_dim
#define JT 256    // j columns per block == blockDim.x
#define TI 16     // i rows per block

typedef _Float16 half2v __attribute__((ext_vector_type(2)));
union H2U { half2v h; unsigned int u; };

// Single fused kernel: no workspace, one launch node.
// Per block: stage W1_i / z_i / b1 / W2 into LDS; compute the 16-row Hi tile
// cooperatively (threads 0..127, b1 folded, f32 accum -> f16 RNE cast, identical
// numerics to the old prep kernel); each thread recomputes Hj for its own j
// column from its z row with wave-uniform W1_j reads (scalarized s_loads).
__global__ __launch_bounds__(256) void MLPDecoder_68092411511098_kernel(
    const float* __restrict__ z, const float* __restrict__ W1,
    const float* __restrict__ b1, const float* __restrict__ W2,
    const float* __restrict__ b2, float* __restrict__ out, int N)
{
    __shared__ float  sWi[D * D];     // W1[:16]  (16x16)
    __shared__ float  sZi[TI * D];    // z rows of the i-tile
    __shared__ float  sB1[D];
    __shared__ float  sW2[D];
    __shared__ half2v sHi[TI * 8];

    const int tid   = threadIdx.x;
    const int jbase = blockIdx.x * JT;
    const int ibase = blockIdx.y * TI;

    // ---- stage small tensors (f32, coalesced float4)
    if (tid < 64)        ((float4*)sWi)[tid]       = ((const float4*)W1)[tid];
    else if (tid < 128)  ((float4*)sZi)[tid - 64]  = ((const float4*)(z + (size_t)ibase * D))[tid - 64];
    else if (tid < 132)  ((float4*)sB1)[tid - 128] = ((const float4*)b1)[tid - 128];
    else if (tid < 136)  ((float4*)sW2)[tid - 132] = ((const float4*)W2)[tid - 132];

    // ---- per-thread z row for j = jbase + tid (L2-resident, 4x dwordx4)
    float zr[D];
    {
        const float4* zsrc = (const float4*)(z + (size_t)(jbase + tid) * D);
        const float4 a = zsrc[0], b = zsrc[1], c = zsrc[2], d = zsrc[3];
        zr[0]=a.x;  zr[1]=a.y;  zr[2]=a.z;  zr[3]=a.w;
        zr[4]=b.x;  zr[5]=b.y;  zr[6]=b.z;  zr[7]=b.w;
        zr[8]=c.x;  zr[9]=c.y;  zr[10]=c.z; zr[11]=c.w;
        zr[12]=d.x; zr[13]=d.y; zr[14]=d.z; zr[15]=d.w;
    }

    __syncthreads();

    // ---- Hi tile: 16 rows x 8 k-pairs = 128 items, one per thread (waves 0-1)
    if (tid < TI * 8) {
        const int r  = tid >> 3;
        const int p  = tid & 7;
        const int k0 = 2 * p, k1 = k0 + 1;
        float a0 = sB1[k0], a1 = sB1[k1];          // fold b1 into i-side
        #pragma unroll
        for (int m = 0; m < D; ++m) {
            const float zf = sZi[r * D + m];
            a0 = fmaf(zf, sWi[m * D + k0], a0);
            a1 = fmaf(zf, sWi[m * D + k1], a1);
        }
        H2U hv; hv.h.x = (_Float16)a0; hv.h.y = (_Float16)a1;
        sHi[r * 8 + p] = hv.h;
    }

    // ---- Hj for own j column; W1_j addresses are wave-uniform -> scalar loads
    half2v vj[8];
    {
        const float* __restrict__ W1j = W1 + D * D;   // rows 16..31
        #pragma unroll
        for (int p = 0; p < 8; ++p) {
            float a0 = 0.f, a1 = 0.f;
            #pragma unroll
            for (int m = 0; m < D; ++m) {
                a0 = fmaf(zr[m], W1j[m * D + 2 * p],     a0);
                a1 = fmaf(zr[m], W1j[m * D + 2 * p + 1], a1);
            }
            H2U hv; hv.h.x = (_Float16)a0; hv.h.y = (_Float16)a1;
            vj[p] = hv.h;
        }
    }

    __syncthreads();

    half2v w2v[8];
    #pragma unroll
    for (int p = 0; p < 8; ++p) {
        H2U wv; wv.h.x = (_Float16)sW2[2 * p]; wv.h.y = (_Float16)sW2[2 * p + 1];
        w2v[p] = wv.h;
    }
    const float b2s = b2[0];
    const half2v zero = {(_Float16)0.f, (_Float16)0.f};

    float* orow = out + (size_t)ibase * N + jbase + tid;
    #pragma unroll 4
    for (int ii = 0; ii < TI; ++ii) {
        const half2v* hrow = &sHi[ii * 8];          // broadcast ds_read_b128 x2
        float acc = b2s;
        #pragma unroll
        for (int p = 0; p < 8; ++p) {
            half2v s = hrow[p] + vj[p];                        // v_pk_add_f16
            half2v r = __builtin_elementwise_max(s, zero);     // v_pk_max_f16
#if __has_builtin(__builtin_amdgcn_fdot2)
            acc = __builtin_amdgcn_fdot2(r, w2v[p], acc, false); // v_dot2_f32_f16
#else
            acc += (float)r.x * (float)w2v[p].x + (float)r.y * (float)w2v[p].y;
#endif
        }
        const float e = __expf(-acc);
        orow[(size_t)ii * N] = __builtin_amdgcn_rcpf(1.0f + e);
    }
}

extern "C" void kernel_launch(void* const* d_in, const int* in_sizes, int n_in,
                              void* d_out, int out_size, void* d_ws, size_t ws_size,
                              hipStream_t stream) {
    const float* z  = (const float*)d_in[0];
    const float* W1 = (const float*)d_in[1];
    const float* b1 = (const float*)d_in[2];
    const float* W2 = (const float*)d_in[3];
    const float* b2 = (const float*)d_in[4];
    float* out = (float*)d_out;

    const int N = in_sizes[0] / D;         // 2048

    (void)d_ws; (void)ws_size;             // workspace deliberately unused

    dim3 grid(N / JT, N / TI);             // (8, 128) = 1024 blocks
    MLPDecoder_68092411511098_kernel<<<grid, dim3(256), 0, stream>>>(
        z, W1, b1, W2, b2, out, N);
}

// Round 2
// 71.451 us; speedup vs baseline: 1.0282x; 1.0198x over previous
//
#include <hip/hip_runtime.h>
#include <math.h>

#define D  16     // latent_dim
#define JT 256    // j columns per block == blockDim.x
#define TI 32     // i rows per block (32: halves per-j Hj recompute vs 16)

typedef _Float16 half2v __attribute__((ext_vector_type(2)));
union H2U { half2v h; unsigned int u; };

// Single fused kernel, no workspace. Per block:
//  - stage W1_i / z_i-tile / b1 / W2 into LDS (coalesced float4)
//  - BEFORE the barrier: each thread computes Hj for its own j column from its
//    z row with wave-uniform W1_j reads (scalarized s_loads) -> overlaps barrier
//  - after barrier: 256 threads compute the 32-row Hi tile (one k-pair each,
//    b1 folded, f32 accum -> f16 RNE, numerics identical to previous rounds)
//  - main loop: 32 outputs/thread via v_pk_add_f16 / v_pk_max_f16 / v_dot2_f32_f16
__global__ __launch_bounds__(256) void MLPDecoder_68092411511098_kernel(
    const float* __restrict__ z, const float* __restrict__ W1,
    const float* __restrict__ b1, const float* __restrict__ W2,
    const float* __restrict__ b2, float* __restrict__ out, int N)
{
    __shared__ float  sWi[D * D];     // W1[:16]  (16x16)
    __shared__ float  sZi[TI * D];    // z rows of the i-tile
    __shared__ float  sB1[D];
    __shared__ float  sW2[D];
    __shared__ half2v sHi[TI * 8];

    const int tid   = threadIdx.x;
    const int jbase = blockIdx.x * JT;
    const int ibase = blockIdx.y * TI;

    // ---- stage small tensors (f32, coalesced float4): 200 float4s
    if (tid < 64)        ((float4*)sWi)[tid]       = ((const float4*)W1)[tid];
    else if (tid < 192)  ((float4*)sZi)[tid - 64]  = ((const float4*)(z + (size_t)ibase * D))[tid - 64];
    else if (tid < 196)  ((float4*)sB1)[tid - 192] = ((const float4*)b1)[tid - 192];
    else if (tid < 200)  ((float4*)sW2)[tid - 196] = ((const float4*)W2)[tid - 196];

    // ---- per-thread z row for j = jbase + tid (L2-resident, 4x dwordx4)
    float zr[D];
    {
        const float4* zsrc = (const float4*)(z + (size_t)(jbase + tid) * D);
        const float4 a = zsrc[0], b = zsrc[1], c = zsrc[2], d = zsrc[3];
        zr[0]=a.x;  zr[1]=a.y;  zr[2]=a.z;  zr[3]=a.w;
        zr[4]=b.x;  zr[5]=b.y;  zr[6]=b.z;  zr[7]=b.w;
        zr[8]=c.x;  zr[9]=c.y;  zr[10]=c.z; zr[11]=c.w;
        zr[12]=d.x; zr[13]=d.y; zr[14]=d.z; zr[15]=d.w;
    }

    // ---- Hj for own j column BEFORE the barrier (no LDS dependence;
    //      W1_j addresses are wave-uniform -> scalar loads overlap sync wait)
    half2v vj[8];
    {
        const float* __restrict__ W1j = W1 + D * D;   // rows 16..31
        #pragma unroll
        for (int p = 0; p < 8; ++p) {
            float a0 = 0.f, a1 = 0.f;
            #pragma unroll
            for (int m = 0; m < D; ++m) {
                a0 = fmaf(zr[m], W1j[m * D + 2 * p],     a0);
                a1 = fmaf(zr[m], W1j[m * D + 2 * p + 1], a1);
            }
            H2U hv; hv.h.x = (_Float16)a0; hv.h.y = (_Float16)a1;
            vj[p] = hv.h;
        }
    }

    __syncthreads();

    // ---- Hi tile: 32 rows x 8 k-pairs = 256 items, exactly one per thread
    {
        const int r  = tid >> 3;
        const int p  = tid & 7;
        const int k0 = 2 * p, k1 = k0 + 1;
        float a0 = sB1[k0], a1 = sB1[k1];          // fold b1 into i-side
        #pragma unroll
        for (int m = 0; m < D; ++m) {
            const float zf = sZi[r * D + m];
            a0 = fmaf(zf, sWi[m * D + k0], a0);
            a1 = fmaf(zf, sWi[m * D + k1], a1);
        }
        H2U hv; hv.h.x = (_Float16)a0; hv.h.y = (_Float16)a1;
        sHi[r * 8 + p] = hv.h;
    }

    half2v w2v[8];
    #pragma unroll
    for (int p = 0; p < 8; ++p) {
        H2U wv; wv.h.x = (_Float16)sW2[2 * p]; wv.h.y = (_Float16)sW2[2 * p + 1];
        w2v[p] = wv.h;
    }
    const float b2s = b2[0];
    const half2v zero = {(_Float16)0.f, (_Float16)0.f};

    __syncthreads();

    float* orow = out + (size_t)ibase * N + jbase + tid;
    #pragma unroll 4
    for (int ii = 0; ii < TI; ++ii) {
        const half2v* hrow = &sHi[ii * 8];          // uniform addr -> broadcast
        float acc = b2s;
        #pragma unroll
        for (int p = 0; p < 8; ++p) {
            half2v s = hrow[p] + vj[p];                        // v_pk_add_f16
            half2v r = __builtin_elementwise_max(s, zero);     // v_pk_max_f16
#if __has_builtin(__builtin_amdgcn_fdot2)
            acc = __builtin_amdgcn_fdot2(r, w2v[p], acc, false); // v_dot2_f32_f16
#else
            acc += (float)r.x * (float)w2v[p].x + (float)r.y * (float)w2v[p].y;
#endif
        }
        const float e = __expf(-acc);
        orow[(size_t)ii * N] = __builtin_amdgcn_rcpf(1.0f + e);
    }
}

extern "C" void kernel_launch(void* const* d_in, const int* in_sizes, int n_in,
                              void* d_out, int out_size, void* d_ws, size_t ws_size,
                              hipStream_t stream) {
    const float* z  = (const float*)d_in[0];
    const float* W1 = (const float*)d_in[1];
    const float* b1 = (const float*)d_in[2];
    const float* W2 = (const float*)d_in[3];
    const float* b2 = (const float*)d_in[4];
    float* out = (float*)d_out;

    const int N = in_sizes[0] / D;         // 2048

    (void)d_ws; (void)ws_size;             // workspace deliberately unused

    dim3 grid(N / JT, N / TI);             // (8, 64) = 512 blocks
    MLPDecoder_68092411511098_kernel<<<grid, dim3(256), 0, stream>>>(
        z, W1, b1, W2, b2, out, N);
}